// Round 5
// baseline (457.108 us; speedup 1.0000x reference)
//
#include <hip/hip_runtime.h>
#include <hip/hip_cooperative_groups.h>
#include <math.h>

namespace cg = cooperative_groups;

#define BB 16
#define NN 2048
#define FF 64
#define SS 4
#define PP 22
#define OO 42
#define NREG 32             // all 2048/64 d2 values kept in VGPRs per lane
#define GRID 1024           // cooperative grid: 4 blocks/CU co-resident
#define PTILES 512          // prep tiles (64 rows each), blocks 0..511
#define WST 68              // LDS row stride (floats): 16B-aligned, non-mult-of-32

__device__ __forceinline__ float readfirstlane_f32(float v) {
    return __uint_as_float((unsigned)__builtin_amdgcn_readfirstlane((int)__float_as_uint(v)));
}
__device__ __forceinline__ int wave_scan_dpp(int x) {
    x += __builtin_amdgcn_update_dpp(0, x, 0x111, 0xf, 0xf, true);  // row_shr:1
    x += __builtin_amdgcn_update_dpp(0, x, 0x112, 0xf, 0xf, true);  // row_shr:2
    x += __builtin_amdgcn_update_dpp(0, x, 0x114, 0xf, 0xf, true);  // row_shr:4
    x += __builtin_amdgcn_update_dpp(0, x, 0x118, 0xf, 0xf, true);  // row_shr:8
    x += __builtin_amdgcn_update_dpp(0, x, 0x142, 0xa, 0xf, true);  // row_bcast:15
    x += __builtin_amdgcn_update_dpp(0, x, 0x143, 0xc, 0xf, true);  // row_bcast:31
    return x;
}
__device__ __forceinline__ int wave_sum_dpp(int x) {
    return __builtin_amdgcn_readlane(wave_scan_dpp(x), 63);
}
__device__ __forceinline__ float wave_fsum_dpp(float x) {
    float t;
    t = __uint_as_float((unsigned)__builtin_amdgcn_update_dpp(0, (int)__float_as_uint(x), 0x111, 0xf, 0xf, true)); x += t;
    t = __uint_as_float((unsigned)__builtin_amdgcn_update_dpp(0, (int)__float_as_uint(x), 0x112, 0xf, 0xf, true)); x += t;
    t = __uint_as_float((unsigned)__builtin_amdgcn_update_dpp(0, (int)__float_as_uint(x), 0x114, 0xf, 0xf, true)); x += t;
    t = __uint_as_float((unsigned)__builtin_amdgcn_update_dpp(0, (int)__float_as_uint(x), 0x118, 0xf, 0xf, true)); x += t;
    t = __uint_as_float((unsigned)__builtin_amdgcn_update_dpp(0, (int)__float_as_uint(x), 0x142, 0xa, 0xf, true)); x += t;
    t = __uint_as_float((unsigned)__builtin_amdgcn_update_dpp(0, (int)__float_as_uint(x), 0x143, 0xc, 0xf, true)); x += t;
    return __uint_as_float((unsigned)__builtin_amdgcn_readlane((int)__float_as_uint(x), 63));
}

// ---- R19: single cooperative kernel: phase A = prep GEMM, grid sync, phase B = kNN ----
// The ~80us total-minus-knn gap survived four different prep structures (R0/R2/R3/R4)
// while prep's arithmetic ceiling is ~10us -> the gap is inter-dispatch overhead, not
// prep compute. One dispatch removes it AND makes the decomposition measurable.
// LDS: one 18.3KB buffer. Phase A uses it as wT[68][68]+bvec (outputs accumulate in
// registers, then overwrite wT after a barrier -> staging tile for coalesced stores).
// Phase B carves 1280B per wave (candk/urow/isel/wsel) from the same buffer.
__global__ __launch_bounds__(256, 4) void fused_kernel(
    const float* __restrict__ x, const float* __restrict__ Ws, const float* __restrict__ bs,
    const float* __restrict__ Wf, const float* __restrict__ bf,
    const float* __restrict__ Wo, const float* __restrict__ bo,
    const int* __restrict__ nnbr,
    float* __restrict__ coords, float* __restrict__ feats, float* __restrict__ xwo,
    float* __restrict__ out)
{
    __shared__ __align__(16) float smem[68 * WST + 68];   // 4692 floats = 18.3 KB

    const int lane = threadIdx.x & 63;
    const int wv   = threadIdx.x >> 6;          // 0..3

    // ================= Phase A: prep GEMM (blocks 0..511, 64 rows each) =============
    if (blockIdx.x < PTILES) {
        float* wT   = smem;                     // [68][WST] transposed weights
        float* bvec = smem + 68 * WST;          // [68]
        const int r0 = blockIdx.x * 64;

        // x row -> 16 float4 in VGPRs (issued before staging; stays live across it)
        const float4* xr = (const float4*)(x + (size_t)(r0 + lane) * FF);
        float4 xv[16];
        #pragma unroll
        for (int k4 = 0; k4 < 16; k4++) xv[k4] = xr[k4];

        // stage weights transposed: coalesced global reads, scattered LDS writes
        {
            int t = threadIdx.x;                // Ws: 64x4 = 256 elems, one each
            int k = t >> 2, s = t & 3;
            wT[s * WST + k] = Ws[t];
        }
        for (int t = threadIdx.x; t < 64 * PP; t += 256) {       // Wf: 1408
            int k = t / PP, c = t - k * PP;
            wT[(4 + c) * WST + k] = Wf[t];
        }
        for (int t = threadIdx.x; t < 64 * OO; t += 256) {       // Wo rows 0..63: 2688
            int k = t / OO, o = t - k * OO;
            wT[(26 + o) * WST + k] = Wo[t];
        }
        if (threadIdx.x < 68) {
            int o = threadIdx.x;
            bvec[o] = o < 4 ? bs[o] : (o < 26 ? bf[o - 4] : bo[o - 26]);
        }
        __syncthreads();

        // wave wv owns cols [17wv,17wv+17); accumulate in REGISTERS (static idx only)
        float acc[17];
        #pragma unroll
        for (int u = 0; u < 17; u++) {
            int o = wv * 17 + u;
            float a0 = bvec[o], a1 = 0.f, a2 = 0.f, a3 = 0.f;
            const float4* wrow = (const float4*)(wT + o * WST);
            #pragma unroll
            for (int k4 = 0; k4 < 16; k4++) {
                float4 w4 = wrow[k4];           // wave-uniform ds_read_b128 broadcast
                a0 = fmaf(xv[k4].x, w4.x, a0);
                a1 = fmaf(xv[k4].y, w4.y, a1);
                a2 = fmaf(xv[k4].z, w4.z, a2);
                a3 = fmaf(xv[k4].w, w4.w, a3);
            }
            acc[u] = (a0 + a1) + (a2 + a3);
        }
        __syncthreads();                        // all wT reads done -> safe to overwrite

        #pragma unroll
        for (int u = 0; u < 17; u++)
            smem[(wv * 17 + u) * WST + lane] = acc[u];   // obuf overlays wT
        __syncthreads();

        // coalesced stores from the LDS tile
        if (threadIdx.x < 64) {
            int r = threadIdx.x;
            float4 cv = make_float4(smem[0 * WST + r], smem[1 * WST + r],
                                    smem[2 * WST + r], smem[3 * WST + r]);
            *((float4*)(coords + (size_t)(r0 + r) * SS)) = cv;
        }
        for (int t = threadIdx.x; t < 32 * PP; t += 256) {       // feats 64x22
            int row = t / 11, c2 = t - row * 11;
            float2 v = make_float2(smem[(4 + 2 * c2) * WST + row],
                                   smem[(4 + 2 * c2 + 1) * WST + row]);
            *((float2*)(feats + (size_t)r0 * PP + 2 * t)) = v;
        }
        for (int t = threadIdx.x; t < 32 * OO; t += 256) {       // xwo 64x42
            int row = t / 21, c2 = t - row * 21;
            float2 v = make_float2(smem[(26 + 2 * c2) * WST + row],
                                   smem[(26 + 2 * c2 + 1) * WST + row]);
            *((float2*)(xwo + (size_t)r0 * OO + 2 * t)) = v;
        }
    }

    cg::this_grid().sync();

    // ================= Phase B: kNN + aggregate + output (R0 body, proven) ==========
    // per-wave LDS carve: 320 floats (1280B, 16B-aligned) per wave
    float* wbase = smem + 320 * wv;
    unsigned long long* candk = (unsigned long long*)wbase;   // [64]  512B
    float* urow = wbase + 128;                                // [48]  16B-aligned
    int*   isel = (int*)(wbase + 176);                        // [64]
    float* wsel = wbase + 240;                                // [64]

    int K = *nnbr; K = K < 2 ? 2 : (K > 64 ? 64 : K);

    const int gw = blockIdx.x * 4 + wv;         // 0..4095
    const int b  = (gw * 8) >> 11;              // all 8 queries in same batch
    const float4* cb = (const float4*)(coords + (size_t)b * NN * SS);
    const float* fb = feats + (size_t)b * NN * PP;

    for (int it = 0; it < 8; it++) {
        const int q = gw * 8 + it;              // 0..32767
        const int i = q & (NN - 1);

        // prefetch the precomputed x-part (overlaps the distance phase)
        float xw = 0.f;
        if (lane < OO) xw = xwo[(size_t)q * OO + lane];

        float4 qv = cb[i];
        const float qx = readfirstlane_f32(qv.x);
        const float qy = readfirstlane_f32(qv.y);
        const float qz = readfirstlane_f32(qv.z);
        const float qw = readfirstlane_f32(qv.w);

        // ---- distances: all 2048 in 32 VGPRs/lane; per-lane min ----
        float d2r[NREG];
        float lmin = INFINITY;
        #pragma unroll 4
        for (int r = 0; r < NREG; r++) {
            float4 c = cb[r * 64 + lane];
            float d0 = qx - c.x, d1 = qy - c.y, d2 = qz - c.z, d3 = qw - c.w;
            float v = d0 * d0 + d1 * d1 + d2 * d2 + d3 * d3;
            d2r[r] = v;
            lmin = fminf(lmin, v);
        }

        float t0 = wave_fsum_dpp(lmin) * (1.0f / 64.0f);

        unsigned loU = 0u, hiU = 0x7F800000u;
        int cLo = 0, cHi = NN;
        int laneLo = 0, laneHi = NREG;
        float tPrev = t0; int cPrev = -1;

        // ---- quad-threshold opening probe (two packed DPP sums) ----
        if (t0 > 1e-30f) {
            float t1 = t0 * 0.75f, t2 = t0 * 0.95f, t3 = t0 * 1.15f, t4 = t0 * 1.40f;
            int l1 = 0, l2 = 0, l3 = 0, l4 = 0;
            #pragma unroll
            for (int r = 0; r < NREG; r++) {
                float v = d2r[r];
                l1 += (v < t1) ? 1 : 0;
                l2 += (v < t2) ? 1 : 0;
                l3 += (v < t3) ? 1 : 0;
                l4 += (v < t4) ? 1 : 0;
            }
            int s12 = wave_sum_dpp(l1 | (l2 << 16));
            int s34 = wave_sum_dpp(l3 | (l4 << 16));
            int c1 = s12 & 0xFFFF, c2 = s12 >> 16, c3 = s34 & 0xFFFF, c4 = s34 >> 16;
            if (c1 >= K)      { hiU = __float_as_uint(t1); cHi = c1; laneHi = l1; }
            else if (c2 >= K) { loU = __float_as_uint(t1); cLo = c1; laneLo = l1;
                                hiU = __float_as_uint(t2); cHi = c2; laneHi = l2; }
            else if (c3 >= K) { loU = __float_as_uint(t2); cLo = c2; laneLo = l2;
                                hiU = __float_as_uint(t3); cHi = c3; laneHi = l3; }
            else if (c4 >= K) { loU = __float_as_uint(t3); cLo = c3; laneLo = l3;
                                hiU = __float_as_uint(t4); cHi = c4; laneHi = l4; }
            else              { loU = __float_as_uint(t4); cLo = c4; laneLo = l4; }
            int bc = -1, bd = 0x7FFFFFFF; float bt = t0;
            int cs[4] = {c1, c2, c3, c4}; float ts[4] = {t1, t2, t3, t4};
            #pragma unroll
            for (int u = 0; u < 4; u++) {
                int d = cs[u] > K ? cs[u] - K : K - cs[u];
                if (cs[u] > 0 && d < bd) { bd = d; bc = cs[u]; bt = ts[u]; }
            }
            if (bc > 0) { tPrev = bt; cPrev = bc; }
            else        { tPrev = t4; cPrev = 0; }
        }

        // ---- dual-threshold bisection rounds (DPP sums) ----
        int probes = 0;
        while (cHi - cLo > 64 && hiU - loU > 1u && probes < 20) {
            unsigned tAU = 0u, tBU = 0u;
            bool fell = false;
            if (cPrev > 0) {
                float g = tPrev * __fsqrt_rn((float)K / (float)cPrev);
                tAU = __float_as_uint(g * 0.88f); tBU = __float_as_uint(g * 1.18f);
            } else if (cPrev == 0) {
                tAU = __float_as_uint(tPrev * 3.0f); tBU = __float_as_uint(tPrev * 9.0f);
            } else fell = true;
            unsigned span = hiU - loU;
            if (fell || !(tAU > loU && tAU < hiU)) tAU = loU + span / 3u;
            if (tAU <= loU) tAU = loU + 1u;
            if (tAU >= hiU) tAU = hiU - 1u;
            if (fell || !(tBU >= tAU && tBU < hiU)) tBU = tAU + (hiU - tAU) / 2u;
            if (tBU < tAU) tBU = tAU;
            if (tBU >= hiU) tBU = hiU - 1u;

            float tA = __uint_as_float(tAU), tB = __uint_as_float(tBU);
            int clA = 0, clB = 0;
            #pragma unroll
            for (int r = 0; r < NREG; r++) {
                clA += (d2r[r] < tA) ? 1 : 0;
                clB += (d2r[r] < tB) ? 1 : 0;
            }
            int tot = wave_sum_dpp(clA | (clB << 16));
            int cA = tot & 0xFFFF, cB = tot >> 16;

            if (cA >= K) { hiU = tAU; cHi = cA; laneHi = clA; }
            else {
                loU = tAU; cLo = cA; laneLo = clA;
                if (cB >= K) { hiU = tBU; cHi = cB; laneHi = clB; }
                else         { loU = tBU; cLo = cB; laneLo = clB; }
            }
            int dA = cA > K ? cA - K : K - cA;
            int dB = cB > K ? cB - K : K - cB;
            if (cA > 0 && dA <= dB) { tPrev = tA; cPrev = cA; }
            else                    { tPrev = tB; cPrev = cB; }
            probes++;
        }

        const float lo = __uint_as_float(loU);
        const float hi = __uint_as_float(hiU);
        const int  need = K - cLo;

        // ---- collect: counts known per lane; DPP scan -> sequential writes ----
        int c1c = laneLo;
        int c2c = laneHi - laneLo;
        if (lane == (i & 63) && loU > 0u) c1c -= 1;
        int pk = c1c | (c2c << 16);
        int inc = wave_scan_dpp(pk);
        int excl = inc - pk;
        int tot  = __builtin_amdgcn_readlane(inc, 63);
        int b1 = excl & 0xFFFF;
        int b2 = excl >> 16;
        const int nbelow = tot & 0xFFFF;
        int ecand = tot >> 16; if (ecand > 64) ecand = 64;
        #pragma unroll
        for (int r = 0; r < NREG; r++) {
            float v = d2r[r];
            int j = r * 64 + lane;
            if ((v < lo) & (j != i)) { isel[b1] = j; wsel[b1] = v; b1++; }
            else if ((v >= lo) & (v < hi)) { if (b2 < 64) candk[b2] = ((unsigned long long)__float_as_uint(v) << 32) | (unsigned)j; b2++; }
        }
        __builtin_amdgcn_wave_barrier();

        // ---- append `need` smallest candidates, skipping self ----
        int nsel;
        if (ecand == need && loU > 0u) {
            if (lane < ecand) {
                int slot = nbelow + lane;
                if (slot < 64) {
                    unsigned long long k2 = candk[lane];
                    isel[slot] = (int)(k2 & 0xFFFFFFFFull);
                    wsel[slot] = __uint_as_float((unsigned)(k2 >> 32));
                }
            }
            nsel = nbelow + ecand;
            if (nsel > 64) nsel = 64;
        } else {
            unsigned long long mykey = ~0ull;
            if (lane < ecand) mykey = candk[lane];
            int mr = 0;
            for (int u = 0; u < ecand; u++) {
                unsigned long long k2 = candk[u];
                mr += (k2 < mykey) ? 1 : 0;
            }
            int mj = (int)(mykey & 0xFFFFFFFFull);
            bool ps = (lane < ecand) & (mr < need) & (mj != i);
            unsigned long long ms = __ballot(ps);
            if (ps) {
                int slot = nbelow + __popcll(ms & ((1ull << lane) - 1ull));
                if (slot < 64) { isel[slot] = mj; wsel[slot] = __uint_as_float((unsigned)(mykey >> 32)); }
            }
            nsel = nbelow + __popcll(ms);
            if (nsel > 64) nsel = 64;
        }
        __builtin_amdgcn_wave_barrier();
        if (lane < nsel) wsel[lane] = __expf(-wsel[lane]);
        __builtin_amdgcn_wave_barrier();

        // ---- weighted max / mean: lanes 0-21 even m, lanes 32-53 odd m ----
        int g = lane >> 5, c = lane & 31;
        float mx = -INFINITY, sm = 0.f;
        if (c < PP) {
            #pragma unroll 8
            for (int m = g; m < nsel; m += 2) {
                int j = isel[m]; float wt = wsel[m];
                float f = fb[(size_t)j * PP + c];
                float wf = wt * f;
                mx = fmaxf(mx, wf); sm += wf;
            }
        }
        float mx2 = __shfl_xor(mx, 32, 64);
        float sm2 = __shfl_xor(sm, 32, 64);
        mx = fmaxf(mx, mx2); sm += sm2;
        if (g == 0 && c < PP) {
            urow[c]      = mx;
            urow[PP + c] = sm / (float)(K - 1);
        }
        __builtin_amdgcn_wave_barrier();

        // ---- epilogue: out[q][o] = tanh(xwo + [max|mean] . Wo[64:,o]) ----
        if (lane < OO) {
            float a0 = xw, a1 = 0.f, a2 = 0.f, a3 = 0.f;
            const float* wo = Wo + FF * OO + lane;
            #pragma unroll
            for (int k4 = 0; k4 < (2 * PP) / 4; k4++) {
                float4 u = *((const float4*)&urow[k4 * 4]);
                a0 = fmaf(u.x, wo[(k4 * 4 + 0) * OO], a0);
                a1 = fmaf(u.y, wo[(k4 * 4 + 1) * OO], a1);
                a2 = fmaf(u.z, wo[(k4 * 4 + 2) * OO], a2);
                a3 = fmaf(u.w, wo[(k4 * 4 + 3) * OO], a3);
            }
            float acc = (a0 + a1) + (a2 + a3);
            float a = acc < -12.f ? -12.f : (acc > 12.f ? 12.f : acc);
            float e2 = __expf(2.f * a);
            out[(size_t)q * OO + lane] = (e2 - 1.f) / (e2 + 1.f);
        }
        __builtin_amdgcn_wave_barrier();
    }
}

// ---------------- fallback two-kernel path (R4, in case coop launch is rejected) ----
__global__ __launch_bounds__(256) void prep_kernel(
    const float* __restrict__ x, const float* __restrict__ Ws, const float* __restrict__ bs,
    const float* __restrict__ Wf, const float* __restrict__ bf,
    const float* __restrict__ Wo, const float* __restrict__ bo,
    float* __restrict__ coords, float* __restrict__ feats, float* __restrict__ xwo)
{
    __shared__ float wT[68 * WST];
    __shared__ float obufT[68 * WST];
    __shared__ float bvec[68];

    const int lane = threadIdx.x & 63;
    const int wv   = threadIdx.x >> 6;
    const int r0   = blockIdx.x * 64;

    const float4* xr = (const float4*)(x + (size_t)(r0 + lane) * FF);
    float4 xv[16];
    #pragma unroll
    for (int k4 = 0; k4 < 16; k4++) xv[k4] = xr[k4];

    {
        int t = threadIdx.x;
        int k = t >> 2, s = t & 3;
        wT[s * WST + k] = Ws[t];
    }
    for (int t = threadIdx.x; t < 64 * PP; t += 256) {
        int k = t / PP, c = t - k * PP;
        wT[(4 + c) * WST + k] = Wf[t];
    }
    for (int t = threadIdx.x; t < 64 * OO; t += 256) {
        int k = t / OO, o = t - k * OO;
        wT[(26 + o) * WST + k] = Wo[t];
    }
    if (threadIdx.x < 68) {
        int o = threadIdx.x;
        bvec[o] = o < 4 ? bs[o] : (o < 26 ? bf[o - 4] : bo[o - 26]);
    }
    __syncthreads();

    for (int u = 0; u < 17; u++) {
        int o = wv * 17 + u;
        float a0 = bvec[o], a1 = 0.f, a2 = 0.f, a3 = 0.f;
        const float4* wrow = (const float4*)(wT + o * WST);
        #pragma unroll
        for (int k4 = 0; k4 < 16; k4++) {
            float4 w4 = wrow[k4];
            a0 = fmaf(xv[k4].x, w4.x, a0);
            a1 = fmaf(xv[k4].y, w4.y, a1);
            a2 = fmaf(xv[k4].z, w4.z, a2);
            a3 = fmaf(xv[k4].w, w4.w, a3);
        }
        obufT[o * WST + lane] = (a0 + a1) + (a2 + a3);
    }
    __syncthreads();

    if (threadIdx.x < 64) {
        int r = threadIdx.x;
        float4 cv = make_float4(obufT[0 * WST + r], obufT[1 * WST + r],
                                obufT[2 * WST + r], obufT[3 * WST + r]);
        *((float4*)(coords + (size_t)(r0 + r) * SS)) = cv;
    }
    for (int t = threadIdx.x; t < 32 * PP; t += 256) {
        int row = t / 11, c2 = t - row * 11;
        float2 v = make_float2(obufT[(4 + 2 * c2) * WST + row],
                               obufT[(4 + 2 * c2 + 1) * WST + row]);
        *((float2*)(feats + (size_t)r0 * PP + 2 * t)) = v;
    }
    for (int t = threadIdx.x; t < 32 * OO; t += 256) {
        int row = t / 21, c2 = t - row * 21;
        float2 v = make_float2(obufT[(26 + 2 * c2) * WST + row],
                               obufT[(26 + 2 * c2 + 1) * WST + row]);
        *((float2*)(xwo + (size_t)r0 * OO + 2 * t)) = v;
    }
}

__global__ __launch_bounds__(128, 4) void knn_out_kernel(
    const float* __restrict__ coords, const float* __restrict__ feats,
    const float* __restrict__ xwo, const float* __restrict__ Wo,
    const int* __restrict__ nnbr, float* __restrict__ out)
{
    const int lane = threadIdx.x & 63;
    const int w    = threadIdx.x >> 6;
    const int q    = blockIdx.x * 2 + w;
    const int b    = q >> 11;
    const int i    = q & (NN - 1);

    int K = *nnbr; K = K < 2 ? 2 : (K > 64 ? 64 : K);

    __shared__ int   isel[2][64];
    __shared__ float wsel[2][64];
    __shared__ unsigned long long candk[2][64];
    __shared__ __align__(16) float urow[2][48];

    float xw = 0.f;
    if (lane < OO) xw = xwo[(size_t)q * OO + lane];

    const float4* cb = (const float4*)(coords + (size_t)b * NN * SS);
    float4 qv = cb[i];
    const float qx = readfirstlane_f32(qv.x);
    const float qy = readfirstlane_f32(qv.y);
    const float qz = readfirstlane_f32(qv.z);
    const float qw = readfirstlane_f32(qv.w);

    float d2r[NREG];
    float lmin = INFINITY;
    #pragma unroll 4
    for (int r = 0; r < NREG; r++) {
        float4 c = cb[r * 64 + lane];
        float d0 = qx - c.x, d1 = qy - c.y, d2 = qz - c.z, d3 = qw - c.w;
        float v = d0 * d0 + d1 * d1 + d2 * d2 + d3 * d3;
        d2r[r] = v;
        lmin = fminf(lmin, v);
    }

    float t0 = wave_fsum_dpp(lmin) * (1.0f / 64.0f);

    unsigned loU = 0u, hiU = 0x7F800000u;
    int cLo = 0, cHi = NN;
    int laneLo = 0, laneHi = NREG;
    float tPrev = t0; int cPrev = -1;

    if (t0 > 1e-30f) {
        float t1 = t0 * 0.75f, t2 = t0 * 0.95f, t3 = t0 * 1.15f, t4 = t0 * 1.40f;
        int l1 = 0, l2 = 0, l3 = 0, l4 = 0;
        #pragma unroll
        for (int r = 0; r < NREG; r++) {
            float v = d2r[r];
            l1 += (v < t1) ? 1 : 0;
            l2 += (v < t2) ? 1 : 0;
            l3 += (v < t3) ? 1 : 0;
            l4 += (v < t4) ? 1 : 0;
        }
        int s12 = wave_sum_dpp(l1 | (l2 << 16));
        int s34 = wave_sum_dpp(l3 | (l4 << 16));
        int c1 = s12 & 0xFFFF, c2 = s12 >> 16, c3 = s34 & 0xFFFF, c4 = s34 >> 16;
        if (c1 >= K)      { hiU = __float_as_uint(t1); cHi = c1; laneHi = l1; }
        else if (c2 >= K) { loU = __float_as_uint(t1); cLo = c1; laneLo = l1;
                            hiU = __float_as_uint(t2); cHi = c2; laneHi = l2; }
        else if (c3 >= K) { loU = __float_as_uint(t2); cLo = c2; laneLo = l2;
                            hiU = __float_as_uint(t3); cHi = c3; laneHi = l3; }
        else if (c4 >= K) { loU = __float_as_uint(t3); cLo = c3; laneLo = l3;
                            hiU = __float_as_uint(t4); cHi = c4; laneHi = l4; }
        else              { loU = __float_as_uint(t4); cLo = c4; laneLo = l4; }
        int bc = -1, bd = 0x7FFFFFFF; float bt = t0;
        int cs[4] = {c1, c2, c3, c4}; float ts[4] = {t1, t2, t3, t4};
        #pragma unroll
        for (int u = 0; u < 4; u++) {
            int d = cs[u] > K ? cs[u] - K : K - cs[u];
            if (cs[u] > 0 && d < bd) { bd = d; bc = cs[u]; bt = ts[u]; }
        }
        if (bc > 0) { tPrev = bt; cPrev = bc; }
        else        { tPrev = t4; cPrev = 0; }
    }

    int probes = 0;
    while (cHi - cLo > 64 && hiU - loU > 1u && probes < 20) {
        unsigned tAU = 0u, tBU = 0u;
        bool fell = false;
        if (cPrev > 0) {
            float g = tPrev * __fsqrt_rn((float)K / (float)cPrev);
            tAU = __float_as_uint(g * 0.88f); tBU = __float_as_uint(g * 1.18f);
        } else if (cPrev == 0) {
            tAU = __float_as_uint(tPrev * 3.0f); tBU = __float_as_uint(tPrev * 9.0f);
        } else fell = true;
        unsigned span = hiU - loU;
        if (fell || !(tAU > loU && tAU < hiU)) tAU = loU + span / 3u;
        if (tAU <= loU) tAU = loU + 1u;
        if (tAU >= hiU) tAU = hiU - 1u;
        if (fell || !(tBU >= tAU && tBU < hiU)) tBU = tAU + (hiU - tAU) / 2u;
        if (tBU < tAU) tBU = tAU;
        if (tBU >= hiU) tBU = hiU - 1u;

        float tA = __uint_as_float(tAU), tB = __uint_as_float(tBU);
        int clA = 0, clB = 0;
        #pragma unroll
        for (int r = 0; r < NREG; r++) {
            clA += (d2r[r] < tA) ? 1 : 0;
            clB += (d2r[r] < tB) ? 1 : 0;
        }
        int tot = wave_sum_dpp(clA | (clB << 16));
        int cA = tot & 0xFFFF, cB = tot >> 16;

        if (cA >= K) { hiU = tAU; cHi = cA; laneHi = clA; }
        else {
            loU = tAU; cLo = cA; laneLo = clA;
            if (cB >= K) { hiU = tBU; cHi = cB; laneHi = clB; }
            else         { loU = tBU; cLo = cB; laneLo = clB; }
        }
        int dA = cA > K ? cA - K : K - cA;
        int dB = cB > K ? cB - K : K - cB;
        if (cA > 0 && dA <= dB) { tPrev = tA; cPrev = cA; }
        else                    { tPrev = tB; cPrev = cB; }
        probes++;
    }

    const float lo = __uint_as_float(loU);
    const float hi = __uint_as_float(hiU);
    const int  need = K - cLo;

    int c1c = laneLo;
    int c2c = laneHi - laneLo;
    if (lane == (i & 63) && loU > 0u) c1c -= 1;
    int pk = c1c | (c2c << 16);
    int inc = wave_scan_dpp(pk);
    int excl = inc - pk;
    int tot  = __builtin_amdgcn_readlane(inc, 63);
    int b1 = excl & 0xFFFF;
    int b2 = excl >> 16;
    const int nbelow = tot & 0xFFFF;
    int ecand = tot >> 16; if (ecand > 64) ecand = 64;
    #pragma unroll
    for (int r = 0; r < NREG; r++) {
        float v = d2r[r];
        int j = r * 64 + lane;
        if ((v < lo) & (j != i)) { isel[w][b1] = j; wsel[w][b1] = v; b1++; }
        else if ((v >= lo) & (v < hi)) { if (b2 < 64) candk[w][b2] = ((unsigned long long)__float_as_uint(v) << 32) | (unsigned)j; b2++; }
    }
    __builtin_amdgcn_wave_barrier();

    int nsel;
    if (ecand == need && loU > 0u) {
        if (lane < ecand) {
            int slot = nbelow + lane;
            if (slot < 64) {
                unsigned long long k2 = candk[w][lane];
                isel[w][slot] = (int)(k2 & 0xFFFFFFFFull);
                wsel[w][slot] = __uint_as_float((unsigned)(k2 >> 32));
            }
        }
        nsel = nbelow + ecand;
        if (nsel > 64) nsel = 64;
    } else {
        unsigned long long mykey = ~0ull;
        if (lane < ecand) mykey = candk[w][lane];
        int mr = 0;
        for (int u = 0; u < ecand; u++) {
            unsigned long long k2 = candk[w][u];
            mr += (k2 < mykey) ? 1 : 0;
        }
        int mj = (int)(mykey & 0xFFFFFFFFull);
        bool ps = (lane < ecand) & (mr < need) & (mj != i);
        unsigned long long ms = __ballot(ps);
        if (ps) {
            int slot = nbelow + __popcll(ms & ((1ull << lane) - 1ull));
            if (slot < 64) { isel[w][slot] = mj; wsel[w][slot] = __uint_as_float((unsigned)(mykey >> 32)); }
        }
        nsel = nbelow + __popcll(ms);
        if (nsel > 64) nsel = 64;
    }
    __builtin_amdgcn_wave_barrier();
    if (lane < nsel) wsel[w][lane] = __expf(-wsel[w][lane]);
    __builtin_amdgcn_wave_barrier();

    const float* fb = feats + (size_t)b * NN * PP;
    int g = lane >> 5, c = lane & 31;
    float mx = -INFINITY, sm = 0.f;
    if (c < PP) {
        #pragma unroll 8
        for (int m = g; m < nsel; m += 2) {
            int j = isel[w][m]; float wt = wsel[w][m];
            float f = fb[(size_t)j * PP + c];
            float wf = wt * f;
            mx = fmaxf(mx, wf); sm += wf;
        }
    }
    float mx2 = __shfl_xor(mx, 32, 64);
    float sm2 = __shfl_xor(sm, 32, 64);
    mx = fmaxf(mx, mx2); sm += sm2;
    if (g == 0 && c < PP) {
        urow[w][c]      = mx;
        urow[w][PP + c] = sm / (float)(K - 1);
    }
    __builtin_amdgcn_wave_barrier();

    if (lane < OO) {
        float a0 = xw, a1 = 0.f, a2 = 0.f, a3 = 0.f;
        const float* wo = Wo + FF * OO + lane;
        #pragma unroll
        for (int k4 = 0; k4 < (2 * PP) / 4; k4++) {
            float4 u = *((const float4*)&urow[w][k4 * 4]);
            a0 = fmaf(u.x, wo[(k4 * 4 + 0) * OO], a0);
            a1 = fmaf(u.y, wo[(k4 * 4 + 1) * OO], a1);
            a2 = fmaf(u.z, wo[(k4 * 4 + 2) * OO], a2);
            a3 = fmaf(u.w, wo[(k4 * 4 + 3) * OO], a3);
        }
        float acc = (a0 + a1) + (a2 + a3);
        float a = acc < -12.f ? -12.f : (acc > 12.f ? 12.f : acc);
        float e2 = __expf(2.f * a);
        out[(size_t)q * OO + lane] = (e2 - 1.f) / (e2 + 1.f);
    }
}

extern "C" void kernel_launch(void* const* d_in, const int* in_sizes, int n_in,
                              void* d_out, int out_size, void* d_ws, size_t ws_size,
                              hipStream_t stream) {
    const float* x  = (const float*)d_in[0];
    const float* Ws = (const float*)d_in[1];
    const float* bs = (const float*)d_in[2];
    const float* Wf = (const float*)d_in[3];
    const float* bf = (const float*)d_in[4];
    const float* Wo = (const float*)d_in[5];
    const float* bo = (const float*)d_in[6];
    const int*   nn = (const int*)d_in[7];
    float* out = (float*)d_out;

    float* coords = (float*)d_ws;                              // 16*2048*4  = 512 KB
    float* feats  = coords + (size_t)BB * NN * SS;             // 16*2048*22 = 2.75 MB
    float* xwo    = feats  + (size_t)BB * NN * PP;             // 32768*42   = 5.5 MB

    void* kargs[] = { (void*)&x, (void*)&Ws, (void*)&bs, (void*)&Wf, (void*)&bf,
                      (void*)&Wo, (void*)&bo, (void*)&nn,
                      (void*)&coords, (void*)&feats, (void*)&xwo, (void*)&out };
    hipError_t err = hipLaunchCooperativeKernel((void*)fused_kernel,
                                                dim3(GRID), dim3(256),
                                                kargs, 0, stream);
    if (err != hipSuccess) {
        // fallback: proven R4 two-kernel path
        prep_kernel<<<PTILES, 256, 0, stream>>>(x, Ws, bs, Wf, bf, Wo, bo, coords, feats, xwo);
        knn_out_kernel<<<(BB * NN) / 2, 128, 0, stream>>>(coords, feats, xwo, Wo, nn, out);
    }
}

// Round 7
// 163.318 us; speedup vs baseline: 2.7989x; 2.7989x over previous
//
#include <hip/hip_runtime.h>
#include <math.h>

#define BB 16
#define NN 2048
#define FF 64
#define SS 4
#define PP 22
#define OO 42
#define NREG 32             // all 2048/64 d2 values kept in VGPRs per lane
#define XBLK 512            // prep blocks: 64 rows each
#define WST 68              // LDS row stride (floats): 16B-aligned, non-mult-of-32

__device__ __forceinline__ float readfirstlane_f32(float v) {
    // value-preserving wave-uniform broadcast (builtin is int->int; must pass bits!)
    return __uint_as_float((unsigned)__builtin_amdgcn_readfirstlane((int)__float_as_uint(v)));
}

// canonical GCN wave64 inclusive scan via DPP: row_shr 1/2/4/8 (bound_ctrl -> OOB reads 0),
// then row_bcast:15 into rows 1,3 and row_bcast:31 into rows 2,3.
__device__ __forceinline__ int wave_scan_dpp(int x) {
    x += __builtin_amdgcn_update_dpp(0, x, 0x111, 0xf, 0xf, true);  // row_shr:1
    x += __builtin_amdgcn_update_dpp(0, x, 0x112, 0xf, 0xf, true);  // row_shr:2
    x += __builtin_amdgcn_update_dpp(0, x, 0x114, 0xf, 0xf, true);  // row_shr:4
    x += __builtin_amdgcn_update_dpp(0, x, 0x118, 0xf, 0xf, true);  // row_shr:8
    x += __builtin_amdgcn_update_dpp(0, x, 0x142, 0xa, 0xf, true);  // row_bcast:15
    x += __builtin_amdgcn_update_dpp(0, x, 0x143, 0xc, 0xf, true);  // row_bcast:31
    return x;
}
// float wave sum: same chain in float domain (0-bits = 0.0f additive identity)
__device__ __forceinline__ float wave_fsum_dpp(float x) {
    float t;
    t = __uint_as_float((unsigned)__builtin_amdgcn_update_dpp(0, (int)__float_as_uint(x), 0x111, 0xf, 0xf, true)); x += t;
    t = __uint_as_float((unsigned)__builtin_amdgcn_update_dpp(0, (int)__float_as_uint(x), 0x112, 0xf, 0xf, true)); x += t;
    t = __uint_as_float((unsigned)__builtin_amdgcn_update_dpp(0, (int)__float_as_uint(x), 0x114, 0xf, 0xf, true)); x += t;
    t = __uint_as_float((unsigned)__builtin_amdgcn_update_dpp(0, (int)__float_as_uint(x), 0x118, 0xf, 0xf, true)); x += t;
    t = __uint_as_float((unsigned)__builtin_amdgcn_update_dpp(0, (int)__float_as_uint(x), 0x142, 0xa, 0xf, true)); x += t;
    t = __uint_as_float((unsigned)__builtin_amdgcn_update_dpp(0, (int)__float_as_uint(x), 0x143, 0xc, 0xf, true)); x += t;
    return __uint_as_float((unsigned)__builtin_amdgcn_readlane((int)__float_as_uint(x), 63));
}

// ---- Kernel 1 (R4-proven, ~1-3us): unified 68-col GEMM, wave-per-64-rows ----
__global__ __launch_bounds__(256) void prep_kernel(
    const float* __restrict__ x, const float* __restrict__ Ws, const float* __restrict__ bs,
    const float* __restrict__ Wf, const float* __restrict__ bf,
    const float* __restrict__ Wo, const float* __restrict__ bo,
    float* __restrict__ coords, float* __restrict__ feats, float* __restrict__ xwo)
{
    __shared__ float wT[68 * WST];      // [o][k] transposed weights
    __shared__ float obufT[68 * WST];   // [o][row-lane] output tile
    __shared__ float bvec[68];

    const int lane = threadIdx.x & 63;
    const int wv   = threadIdx.x >> 6;          // 0..3
    const int r0   = blockIdx.x * 64;

    const float4* xr = (const float4*)(x + (size_t)(r0 + lane) * FF);
    float4 xv[16];
    #pragma unroll
    for (int k4 = 0; k4 < 16; k4++) xv[k4] = xr[k4];

    {
        int t = threadIdx.x;                    // Ws: 64x4 = 256 elems
        int k = t >> 2, s = t & 3;
        wT[s * WST + k] = Ws[t];
    }
    for (int t = threadIdx.x; t < 64 * PP; t += 256) {       // Wf: 1408
        int k = t / PP, c = t - k * PP;
        wT[(4 + c) * WST + k] = Wf[t];
    }
    for (int t = threadIdx.x; t < 64 * OO; t += 256) {       // Wo rows 0..63: 2688
        int k = t / OO, o = t - k * OO;
        wT[(26 + o) * WST + k] = Wo[t];
    }
    if (threadIdx.x < 68) {
        int o = threadIdx.x;
        bvec[o] = o < 4 ? bs[o] : (o < 26 ? bf[o - 4] : bo[o - 26]);
    }
    __syncthreads();

    for (int u = 0; u < 17; u++) {
        int o = wv * 17 + u;
        float a0 = bvec[o], a1 = 0.f, a2 = 0.f, a3 = 0.f;
        const float4* wrow = (const float4*)(wT + o * WST);
        #pragma unroll
        for (int k4 = 0; k4 < 16; k4++) {
            float4 w4 = wrow[k4];               // wave-uniform ds_read_b128 broadcast
            a0 = fmaf(xv[k4].x, w4.x, a0);
            a1 = fmaf(xv[k4].y, w4.y, a1);
            a2 = fmaf(xv[k4].z, w4.z, a2);
            a3 = fmaf(xv[k4].w, w4.w, a3);
        }
        obufT[o * WST + lane] = (a0 + a1) + (a2 + a3);
    }
    __syncthreads();

    if (threadIdx.x < 64) {
        int r = threadIdx.x;
        float4 cv = make_float4(obufT[0 * WST + r], obufT[1 * WST + r],
                                obufT[2 * WST + r], obufT[3 * WST + r]);
        *((float4*)(coords + (size_t)(r0 + r) * SS)) = cv;
    }
    for (int t = threadIdx.x; t < 32 * PP; t += 256) {       // feats 64x22
        int row = t / 11, c2 = t - row * 11;
        float2 v = make_float2(obufT[(4 + 2 * c2) * WST + row],
                               obufT[(4 + 2 * c2 + 1) * WST + row]);
        *((float2*)(feats + (size_t)r0 * PP + 2 * t)) = v;
    }
    for (int t = threadIdx.x; t < 32 * OO; t += 256) {       // xwo 64x42
        int row = t / 21, c2 = t - row * 21;
        float2 v = make_float2(obufT[(26 + 2 * c2) * WST + row],
                               obufT[(26 + 2 * c2 + 1) * WST + row]);
        *((float2*)(xwo + (size_t)r0 * OO + 2 * t)) = v;
    }
}

// ---- Kernel 2 (R21): wave-per-query kNN, single-window selection, BRACKETED search ----
// R20's retry loop could oscillate around the [K,64] window and exit unconverged
// (absmax 0.47). Fix: bits-space bracket with invariant count(bLo) < K, count(bHi) > 64;
// every failed probe tightens the bracket; power-law proposals are clamped inside the
// open bracket and replaced by the bits midpoint from attempt 3 on (pure bisection ->
// guaranteed termination: with distinct d2 values every integer count is achieved, so
// a threshold with count in [K,64] exists and interval halving finds it).
// lo=0 => self (d2=0) is rank 0, excluded by j!=i => exactly K-1 kept, matching
// top_k's self-drop + tie-by-lower-index ((d2bits<<32)|j key order).
__global__ __launch_bounds__(128, 4) void knn_out_kernel(
    const float* __restrict__ coords, const float* __restrict__ feats,
    const float* __restrict__ xwo, const float* __restrict__ Wo,
    const int* __restrict__ nnbr, float* __restrict__ out)
{
    const int lane = threadIdx.x & 63;
    const int w    = threadIdx.x >> 6;
    const int q    = blockIdx.x * 2 + w;       // 0..32767
    const int b    = q >> 11;
    const int i    = q & (NN - 1);

    int K = *nnbr; K = K < 2 ? 2 : (K > 64 ? 64 : K);

    __shared__ int   isel[2][64];
    __shared__ float wsel[2][64];
    __shared__ unsigned long long candk[2][64];   // (d2bits<<32)|j packed keys
    __shared__ __align__(16) float urow[2][48];   // [max | mean], 44 used

    // prefetch the precomputed x-part of the output (overlaps the distance phase)
    float xw = 0.f;
    if (lane < OO) xw = xwo[(size_t)q * OO + lane];

    const float4* cb = (const float4*)(coords + (size_t)b * NN * SS);
    float4 qv = cb[i];
    const float qx = readfirstlane_f32(qv.x);
    const float qy = readfirstlane_f32(qv.y);
    const float qz = readfirstlane_f32(qv.z);
    const float qw = readfirstlane_f32(qv.w);

    // ---- distances: all 2048 kept in 32 VGPRs/lane; track per-lane min ----
    float d2r[NREG];
    float lmin = INFINITY;
    #pragma unroll 4
    for (int r = 0; r < NREG; r++) {
        float4 c = cb[r * 64 + lane];
        float d0 = qx - c.x, d1 = qy - c.y, d2 = qz - c.z, d3 = qw - c.w;
        float v = d0 * d0 + d1 * d1 + d2 * d2 + d3 * d3;
        d2r[r] = v;
        lmin = fminf(lmin, v);
    }

    // ---- t0: mean of per-lane minima ~ local scale (adapts to density) ----
    float t0 = wave_fsum_dpp(lmin) * (1.0f / 64.0f);
    if (!(t0 > 1e-30f)) t0 = 1e-30f;

    // ---- bracketed single-window search: count(hi) in [K, 64] ----
    const float targetc = 0.5f * (float)(K + 64);          // 52 for K=40
    unsigned bLoU = 0u;              // invariant: count(< bLo) < K
    unsigned bHiU = 0x7F800000u;     // invariant: count(< bHi) > 64
    unsigned hiU  = __float_as_uint(t0 * __fsqrt_rn(targetc * (1.0f / 40.0f)));
    if (hiU <= bLoU) hiU = bLoU + 1u;
    if (hiU >= bHiU) hiU = bHiU - 1u;

    int ecand = 0, lcnt = 0, incl = 0;
    for (int att = 0; att < 32; att++) {
        float hi = __uint_as_float(hiU);
        lcnt = 0;
        #pragma unroll
        for (int r = 0; r < NREG; r++) lcnt += (d2r[r] < hi) ? 1 : 0;
        incl  = wave_scan_dpp(lcnt);                       // inclusive scan
        ecand = __builtin_amdgcn_readlane(incl, 63);       // exact wave count
        if (ecand >= K && ecand <= 64) break;

        unsigned prop;
        if (ecand < K) {
            bLoU = hiU;
            float denom = (float)(ecand < 2 ? 2 : ecand);
            float sc = __fsqrt_rn(targetc / denom);        // count ~ hi^2 power law
            sc = sc > 4.0f ? 4.0f : sc;
            prop = __float_as_uint(hi * sc);
        } else {                                           // ecand > 64
            bHiU = hiU;
            prop = __float_as_uint(hi * __fsqrt_rn(targetc / (float)ecand));
        }
        if (bHiU - bLoU <= 1u) break;                      // mass-tie pathological only
        if (att >= 3 || !(prop > bLoU && prop < bHiU))     // force bisection: converges
            prop = bLoU + ((bHiU - bLoU) >> 1);
        if (prop <= bLoU) prop = bLoU + 1u;
        if (prop >= bHiU) prop = bHiU - 1u;
        hiU = prop;
    }
    const float hi = __uint_as_float(hiU);
    if (ecand > 64) ecand = 64;      // unreachable for distinct d2; safety clamp

    // ---- collect: per-lane base from exclusive scan; sequential writes ----
    int b2 = incl - lcnt;
    #pragma unroll
    for (int r = 0; r < NREG; r++) {
        float v = d2r[r];
        if (v < hi) {
            if (b2 < 64)
                candk[w][b2] = ((unsigned long long)__float_as_uint(v) << 32) | (unsigned)(r * 64 + lane);
            b2++;
        }
    }
    __builtin_amdgcn_wave_barrier();

    // ---- rank candidates; keep K smallest (self = rank 0), skip self ----
    unsigned long long mykey = ~0ull;
    if (lane < ecand) mykey = candk[w][lane];
    int mr = 0;
    for (int u = 0; u < ecand; u++) {            // ds_read_b64 broadcast, conflict-free
        unsigned long long ku = candk[w][u];
        mr += (ku < mykey) ? 1 : 0;
    }
    int mj = (int)(mykey & 0xFFFFFFFFull);
    bool ps = (lane < ecand) & (mr < K) & (mj != i);
    unsigned long long ms = __ballot(ps);
    if (ps) {
        int slot = __popcll(ms & ((1ull << lane) - 1ull));
        isel[w][slot] = mj;
        wsel[w][slot] = __uint_as_float((unsigned)(mykey >> 32));
    }
    int nsel = __popcll(ms);                     // expect K-1 = 39
    if (nsel > 64) nsel = 64;
    __builtin_amdgcn_wave_barrier();
    if (lane < nsel) wsel[w][lane] = __expf(-wsel[w][lane]);
    __builtin_amdgcn_wave_barrier();

    // ---- weighted max / mean: lanes 0-21 do even m, lanes 32-53 odd m ----
    const float* fb = feats + (size_t)b * NN * PP;
    int g = lane >> 5, c = lane & 31;
    float mx = -INFINITY, sm = 0.f;
    if (c < PP) {
        #pragma unroll 8
        for (int m = g; m < nsel; m += 2) {
            int j = isel[w][m]; float wt = wsel[w][m];
            float f = fb[(size_t)j * PP + c];
            float wf = wt * f;
            mx = fmaxf(mx, wf); sm += wf;
        }
    }
    float mx2 = __shfl_xor(mx, 32, 64);
    float sm2 = __shfl_xor(sm, 32, 64);
    mx = fmaxf(mx, mx2); sm += sm2;
    if (g == 0 && c < PP) {
        urow[w][c]      = mx;
        urow[w][PP + c] = sm / (float)(K - 1);
    }
    __builtin_amdgcn_wave_barrier();

    // ---- epilogue: out[q][o] = tanh(xwo + [max|mean] . Wo[64:,o]), lanes 0-41 ----
    if (lane < OO) {
        float a0 = xw, a1 = 0.f, a2 = 0.f, a3 = 0.f;
        const float* wo = Wo + FF * OO + lane;   // rows 64..107, coalesced across lanes
        #pragma unroll
        for (int k4 = 0; k4 < (2 * PP) / 4; k4++) {
            float4 u = *((const float4*)&urow[w][k4 * 4]);   // ds_read_b128 broadcast
            a0 = fmaf(u.x, wo[(k4 * 4 + 0) * OO], a0);
            a1 = fmaf(u.y, wo[(k4 * 4 + 1) * OO], a1);
            a2 = fmaf(u.z, wo[(k4 * 4 + 2) * OO], a2);
            a3 = fmaf(u.w, wo[(k4 * 4 + 3) * OO], a3);
        }
        float acc = (a0 + a1) + (a2 + a3);
        float a = acc < -12.f ? -12.f : (acc > 12.f ? 12.f : acc);
        float e2 = __expf(2.f * a);
        out[(size_t)q * OO + lane] = (e2 - 1.f) / (e2 + 1.f);
    }
}

extern "C" void kernel_launch(void* const* d_in, const int* in_sizes, int n_in,
                              void* d_out, int out_size, void* d_ws, size_t ws_size,
                              hipStream_t stream) {
    const float* x  = (const float*)d_in[0];
    const float* Ws = (const float*)d_in[1];
    const float* bs = (const float*)d_in[2];
    const float* Wf = (const float*)d_in[3];
    const float* bf = (const float*)d_in[4];
    const float* Wo = (const float*)d_in[5];
    const float* bo = (const float*)d_in[6];
    const int*   nn = (const int*)d_in[7];
    float* out = (float*)d_out;

    float* coords = (float*)d_ws;                              // 16*2048*4  = 512 KB
    float* feats  = coords + (size_t)BB * NN * SS;             // 16*2048*22 = 2.75 MB
    float* xwo    = feats  + (size_t)BB * NN * PP;             // 32768*42   = 5.5 MB

    prep_kernel<<<XBLK, 256, 0, stream>>>(x, Ws, bs, Wf, bf, Wo, bo, coords, feats, xwo);
    knn_out_kernel<<<(BB * NN) / 2, 128, 0, stream>>>(coords, feats, xwo, Wo, nn, out);
}